// Round 3
// baseline (659.449 us; speedup 1.0000x reference)
//
#include <hip/hip_runtime.h>

#define BB    64
#define TT    256
#define EMBD  300
#define HIDD  512
#define OUTC  10
#define THETA 10.0
#define FUTN  12     // >= Kr-1 (Kr expected 11)
#define KSMAX 80     // >= Ks (expected 77), srm zero-padded
#define XSTR  260    // LDS x row stride (doubles)
#define HSTR  265    // LDS h row stride (doubles), odd -> 16 distinct banks

// ---------------- prep: gather+transpose x -> xg[b][e][t] f32; W2 -> f64 ----
__global__ __launch_bounds__(256)
void prep_kernel(const int* __restrict__ feed, const float* __restrict__ emb,
                 const float* __restrict__ W2, float* __restrict__ xg,
                 double* __restrict__ w2d)
{
    if (blockIdx.y == 8) {             // W2 f32 -> f64 (5120 elems)
        const int k = blockIdx.x * 256 + threadIdx.x;
        if (k < OUTC * HIDD) w2d[k] = (double)W2[k];
        return;
    }
    __shared__ float xt[32][305];
    __shared__ int   idx32[32];
    const int tid = threadIdx.x;
    const int b   = blockIdx.x;
    const int t0  = blockIdx.y * 32;

    if (tid < 32) idx32[tid] = feed[b * TT + t0 + tid];
    __syncthreads();
    for (int t = tid >> 6; t < 32; t += 4) {
        const size_t row = (size_t)idx32[t] * EMBD;
        for (int e = (tid & 63); e < EMBD; e += 64)
            xt[t][e] = emb[row + e];
    }
    __syncthreads();
    const int tl = tid & 7;
    for (int e = tid >> 3; e < EMBD; e += 32) {
        float4 v;
        v.x = xt[4 * tl + 0][e];
        v.y = xt[4 * tl + 1][e];
        v.z = xt[4 * tl + 2][e];
        v.w = xt[4 * tl + 3][e];
        *(float4*)&xg[((size_t)b * EMBD + e) * TT + t0 + 4 * tl] = v;
    }
}

// ---------------- layer 1: GEMM (f64) + FIR + spike scan --------------------
__global__ __launch_bounds__(256, 4)
void layer1_kernel(const float* __restrict__ xg, const float* __restrict__ W1,
                   const float* __restrict__ srm, const float* __restrict__ refk,
                   unsigned char* __restrict__ s1, int Ks, int Kr)
{
    __shared__ union { double x[16 * XSTR]; double h[16 * HSTR]; } A; // 33.9 KB
    __shared__ union { double w[16 * 18]; unsigned char s[16 * 260]; } B;
    __shared__ double srm_sm[KSMAX];

    const int tid = threadIdx.x;
    const int b   = blockIdx.x;
    const int c0  = blockIdx.y * 16;

    if (tid < KSMAX) srm_sm[tid] = (tid < Ks) ? (double)srm[tid] : 0.0;

    const int cg = tid & 3,  tg = tid >> 2;    // GEMM tile: c=4cg+j, t=4tg+i
    const int tl = tid & 63, wv = tid >> 6;    // x staging
    const int ew = tid & 15, cw = tid >> 4;    // w staging

    double acc[4][4];
#pragma unroll
    for (int i = 0; i < 4; ++i)
#pragma unroll
        for (int j = 0; j < 4; ++j) acc[i][j] = 0.0;

    float4 xr[4];
    float  wr = 0.f;

    // stage chunk 0 (16 e)
#pragma unroll
    for (int r = 0; r < 4; ++r)
        xr[r] = *(const float4*)&xg[((size_t)b * EMBD + 4 * wv + r) * TT + 4 * tl];
    wr = W1[(size_t)(c0 + cw) * EMBD + ew];
#pragma unroll
    for (int r = 0; r < 4; ++r) {
        double* d = &A.x[(4 * wv + r) * XSTR + 4 * tl];
        d[0] = (double)xr[r].x; d[1] = (double)xr[r].y;
        d[2] = (double)xr[r].z; d[3] = (double)xr[r].w;
    }
    B.w[ew * 18 + cw] = (double)wr;
    __syncthreads();

    const int NCH = (EMBD + 15) / 16;  // 19
    for (int ch = 0; ch < NCH; ++ch) {
        const int ecur = min(16, EMBD - ch * 16);
        const int e0n  = (ch + 1) * 16;
        const int ecn  = EMBD - e0n;
        if (ch + 1 < NCH) {            // register prefetch of next chunk
#pragma unroll
            for (int r = 0; r < 4; ++r) {
                const int e = 4 * wv + r;
                if (e < ecn)
                    xr[r] = *(const float4*)&xg[((size_t)b * EMBD + e0n + e) * TT + 4 * tl];
            }
            if (ew < ecn) wr = W1[(size_t)(c0 + cw) * EMBD + e0n + ew];
        }
        const double* xp = &A.x[4 * tg];
        const double* wp = &B.w[4 * cg];
#pragma unroll 4
        for (int e = 0; e < ecur; ++e) {
            const double2 x01 = *(const double2*)xp;
            const double2 x23 = *(const double2*)(xp + 2);
            const double2 wa  = *(const double2*)wp;
            const double2 wb  = *(const double2*)(wp + 2);
            acc[0][0] = fma(x01.x, wa.x, acc[0][0]);
            acc[0][1] = fma(x01.x, wa.y, acc[0][1]);
            acc[0][2] = fma(x01.x, wb.x, acc[0][2]);
            acc[0][3] = fma(x01.x, wb.y, acc[0][3]);
            acc[1][0] = fma(x01.y, wa.x, acc[1][0]);
            acc[1][1] = fma(x01.y, wa.y, acc[1][1]);
            acc[1][2] = fma(x01.y, wb.x, acc[1][2]);
            acc[1][3] = fma(x01.y, wb.y, acc[1][3]);
            acc[2][0] = fma(x23.x, wa.x, acc[2][0]);
            acc[2][1] = fma(x23.x, wa.y, acc[2][1]);
            acc[2][2] = fma(x23.x, wb.x, acc[2][2]);
            acc[2][3] = fma(x23.x, wb.y, acc[2][3]);
            acc[3][0] = fma(x23.y, wa.x, acc[3][0]);
            acc[3][1] = fma(x23.y, wa.y, acc[3][1]);
            acc[3][2] = fma(x23.y, wb.x, acc[3][2]);
            acc[3][3] = fma(x23.y, wb.y, acc[3][3]);
            xp += XSTR;
            wp += 18;
        }
        __syncthreads();               // all reads of A.x/B.w done
        if (ch + 1 < NCH) {
#pragma unroll
            for (int r = 0; r < 4; ++r) {
                const int e = 4 * wv + r;
                if (e < ecn) {
                    double* d = &A.x[e * XSTR + 4 * tl];
                    d[0] = (double)xr[r].x; d[1] = (double)xr[r].y;
                    d[2] = (double)xr[r].z; d[3] = (double)xr[r].w;
                }
            }
            if (ew < ecn) B.w[ew * 18 + cw] = (double)wr;
            __syncthreads();
        }
    }

    // h (pre-psp membrane) -> LDS [c][t], stride HSTR
#pragma unroll
    for (int i = 0; i < 4; ++i)
#pragma unroll
        for (int j = 0; j < 4; ++j)
            A.h[(4 * cg + j) * HSTR + (4 * tg + i)] = acc[i][j];
    __syncthreads();

    // psp FIR: two passes of 8 outputs (32 VGPR live -> no spill),
    // j ascending 0..KSMAX-1 => bit-identical to previous rounds
    const int cf = tid & 15, tb = tid >> 4;
    const double* hrow = &A.h[cf * HSTR];
    double pout[16];
#pragma unroll
    for (int k = 0; k < 16; ++k) pout[k] = 0.0;
#pragma unroll
    for (int pp = 0; pp < 2; ++pp) {
        const int t0 = tb * 16 + pp * 8;
        double win[8];
#pragma unroll
        for (int k = 0; k < 8; ++k) win[k] = hrow[t0 + k];
        for (int jb = 0; jb < KSMAX; jb += 8) {
#pragma unroll
            for (int jj = 0; jj < 8; ++jj) {
                const double sj = srm_sm[jb + jj];
#pragma unroll
                for (int i = 0; i < 8; ++i)
                    pout[pp * 8 + i] = fma(win[(8 + i - jj) & 7], sj, pout[pp * 8 + i]);
                const int idx = t0 - (jb + jj) - 1;
                win[(7 - jj) & 7] = (idx >= 0) ? hrow[idx] : 0.0;
            }
        }
    }
    __syncthreads();                   // all FIR reads done before overwrite
#pragma unroll
    for (int k = 0; k < 16; ++k)
        A.h[cf * HSTR + tb * 16 + k] = pout[k];
    __syncthreads();

    // spike scan: 16 lanes, one per channel
    if (tid < 16) {
        double fut[FUTN], rsh[FUTN];
#pragma unroll
        for (int i = 0; i < FUTN; ++i) {
            fut[i] = (i + 1 < Kr) ? (double)refk[i + 1] : 0.0;
            rsh[i] = 0.0;
        }
        const double*  hr = &A.h[tid * HSTR];
        unsigned char* sr = &B.s[tid * 260];
        for (int t = 0; t < TT; ++t) {
            const double m  = hr[t] + rsh[0];
            const double sv = (m >= THETA) ? 1.0 : 0.0;
#pragma unroll
            for (int i = 0; i < FUTN - 1; ++i) rsh[i] = fma(sv, fut[i], rsh[i + 1]);
            rsh[FUTN - 1] = sv * fut[FUTN - 1];
            sr[t] = (unsigned char)(sv != 0.0 ? 1 : 0);
        }
    }
    __syncthreads();

    // spikes -> global (uchar, coalesced via uint)
    {
        const int tl2 = tid & 63;
#pragma unroll
        for (int r = 0; r < 4; ++r) {
            const int c = (tid >> 6) + 4 * r;
            const unsigned int v = *(const unsigned int*)&B.s[c * 260 + 4 * tl2];
            *(unsigned int*)&s1[((size_t)b * HIDD + c0 + c) * TT + 4 * tl2] = v;
        }
    }
}

// ---------------- layer 2a: m2 = W2 . s1 (f64), parallel over b x t ---------
__global__ __launch_bounds__(256)
void layer2a_kernel(const unsigned char* __restrict__ s1,
                    const double* __restrict__ w2d, double* __restrict__ m2)
{
    __shared__ double w2l[OUTC * HIDD];    // 40 KB
    __shared__ double red[4][OUTC][65];    // 20.8 KB

    const int tid = threadIdx.x;
    const int b = blockIdx.x, q = blockIdx.y;
    const int tl = tid & 63, hq = tid >> 6;
    const int t  = q * 64 + tl;

    for (int u = tid; u < OUTC * HIDD; u += 256) w2l[u] = w2d[u];
    __syncthreads();

    double p[OUTC];
#pragma unroll
    for (int oc = 0; oc < OUTC; ++oc) p[oc] = 0.0;

    const unsigned char* sp = s1 + ((size_t)b * HIDD + hq * 128) * TT + t;
    for (int h0 = 0; h0 < 128; ++h0) {
        const double sv = (double)sp[(size_t)h0 * TT];
        const int h = hq * 128 + h0;
#pragma unroll
        for (int oc = 0; oc < OUTC; ++oc)
            p[oc] = fma(sv, w2l[oc * HIDD + h], p[oc]);
    }
#pragma unroll
    for (int oc = 0; oc < OUTC; ++oc) red[hq][oc][tl] = p[oc];
    __syncthreads();

    for (int u = tid; u < OUTC * 64; u += 256) {
        const int oc = u >> 6, t2 = u & 63;
        const double s = ((red[0][oc][t2] + red[1][oc][t2]) +
                          red[2][oc][t2]) + red[3][oc][t2];
        m2[((size_t)b * OUTC + oc) * TT + q * 64 + t2] = s;
    }
}

// ---------------- layer 2b: FIR + spike scan on m2 --------------------------
__global__ __launch_bounds__(256)
void layer2b_kernel(const double* __restrict__ m2, const float* __restrict__ srm,
                    const float* __restrict__ refk, float* __restrict__ out,
                    int Ks, int Kr)
{
    __shared__ double mh[OUTC][257];
    __shared__ double uh[OUTC][257];
    __shared__ double srm_sm[KSMAX];
    __shared__ unsigned char s2[OUTC][260];

    const int tid = threadIdx.x;       // == t
    const int b   = blockIdx.x;

    if (tid < KSMAX) srm_sm[tid] = (tid < Ks) ? (double)srm[tid] : 0.0;
    for (int u = tid; u < OUTC * TT; u += 256)
        mh[u >> 8][u & 255] = m2[(size_t)b * OUTC * TT + u];
    __syncthreads();

    double p[OUTC];
#pragma unroll
    for (int oc = 0; oc < OUTC; ++oc) p[oc] = 0.0;
    for (int j = 0; j < KSMAX; ++j) {
        const int idx = tid - j;
        if (idx >= 0) {
            const double sj = srm_sm[j];
#pragma unroll
            for (int oc = 0; oc < OUTC; ++oc)
                p[oc] = fma(mh[oc][idx], sj, p[oc]);
        }
    }
#pragma unroll
    for (int oc = 0; oc < OUTC; ++oc) uh[oc][tid] = p[oc];
    __syncthreads();

    if (tid < OUTC) {
        double fut[FUTN], rsh[FUTN];
#pragma unroll
        for (int i = 0; i < FUTN; ++i) {
            fut[i] = (i + 1 < Kr) ? (double)refk[i + 1] : 0.0;
            rsh[i] = 0.0;
        }
        for (int t = 0; t < TT; ++t) {
            const double m  = uh[tid][t] + rsh[0];
            const double sv = (m >= THETA) ? 1.0 : 0.0;
#pragma unroll
            for (int i = 0; i < FUTN - 1; ++i) rsh[i] = fma(sv, fut[i], rsh[i + 1]);
            rsh[FUTN - 1] = sv * fut[FUTN - 1];
            s2[tid][t] = (unsigned char)(sv != 0.0 ? 1 : 0);
        }
    }
    __syncthreads();

    for (int u = tid; u < OUTC * TT; u += 256)
        out[(size_t)b * OUTC * TT + u] = (float)s2[u >> 8][u & 255];
}

extern "C" void kernel_launch(void* const* d_in, const int* in_sizes, int n_in,
                              void* d_out, int out_size, void* d_ws, size_t ws_size,
                              hipStream_t stream)
{
    const int*   feed = (const int*)  d_in[0];
    const float* emb  = (const float*)d_in[1];
    const float* W1   = (const float*)d_in[2];
    const float* W2   = (const float*)d_in[3];
    const float* srm  = (const float*)d_in[4];
    const float* refk = (const float*)d_in[5];
    const int Ks = in_sizes[4];
    const int Kr = in_sizes[5];

    unsigned char* s1c = (unsigned char*)d_ws;                       // 8,388,608 B
    float*  xg  = (float*) ((char*)d_ws + 8388608);                  // 19,660,800 B
    double* m2  = (double*)((char*)d_ws + 8388608);                  // overlaps xg (dead after layer1)
    double* w2d = (double*)((char*)d_ws + 8388608 + 19660800);       // 40,960 B
    float*  out = (float*)d_out;

    prep_kernel   <<<dim3(BB, 9),  256, 0, stream>>>(feed, emb, W2, xg, w2d);
    layer1_kernel <<<dim3(BB, 32), 256, 0, stream>>>(xg, W1, srm, refk, s1c, Ks, Kr);
    layer2a_kernel<<<dim3(BB, 4),  256, 0, stream>>>(s1c, w2d, m2);
    layer2b_kernel<<<dim3(BB),     256, 0, stream>>>(m2, srm, refk, out, Ks, Kr);
}

// Round 4
// 577.608 us; speedup vs baseline: 1.1417x; 1.1417x over previous
//
#include <hip/hip_runtime.h>

#define BB    64
#define TT    256
#define EMBD  300
#define HIDD  512
#define OUTC  10
#define THETA 10.0
#define FUTN  12     // >= Kr-1 (Kr expected 11)
#define KSMAX 80     // >= Ks (expected 77), srm zero-padded
#define XSTR  260    // LDS x row stride (floats)
#define WSTR  18     // LDS w row stride (doubles)
#define HSTR  265    // LDS h row stride (doubles), odd -> 16 distinct banks

// ---------------- prep: gather+transpose x -> xg[b][e][t] f32; W2 -> f64 ----
__global__ __launch_bounds__(256)
void prep_kernel(const int* __restrict__ feed, const float* __restrict__ emb,
                 const float* __restrict__ W2, float* __restrict__ xg,
                 double* __restrict__ w2d)
{
    if (blockIdx.y == 8) {             // W2 f32 -> f64 (5120 elems)
        const int k = blockIdx.x * 256 + threadIdx.x;
        if (k < OUTC * HIDD) w2d[k] = (double)W2[k];
        return;
    }
    __shared__ float xt[32][305];
    __shared__ int   idx32[32];
    const int tid = threadIdx.x;
    const int b   = blockIdx.x;
    const int t0  = blockIdx.y * 32;

    if (tid < 32) idx32[tid] = feed[b * TT + t0 + tid];
    __syncthreads();
    for (int t = tid >> 6; t < 32; t += 4) {
        const size_t row = (size_t)idx32[t] * EMBD;
        for (int e = (tid & 63); e < EMBD; e += 64)
            xt[t][e] = emb[row + e];
    }
    __syncthreads();
    const int tl = tid & 7;
    for (int e = tid >> 3; e < EMBD; e += 32) {
        float4 v;
        v.x = xt[4 * tl + 0][e];
        v.y = xt[4 * tl + 1][e];
        v.z = xt[4 * tl + 2][e];
        v.w = xt[4 * tl + 3][e];
        *(float4*)&xg[((size_t)b * EMBD + e) * TT + t0 + 4 * tl] = v;
    }
}

// ---------------- layer 1: GEMM (f64 acc) + FIR + spike scan ----------------
__global__ __launch_bounds__(256, 2)
void layer1_kernel(const float* __restrict__ xg, const float* __restrict__ W1,
                   const float* __restrict__ srm, const float* __restrict__ refk,
                   unsigned char* __restrict__ s1, int Ks, int Kr)
{
    __shared__ union { float x[16 * XSTR]; double h[16 * HSTR]; } A; // 33.9 KB
    __shared__ union { double w[16 * WSTR]; unsigned char s[16 * 260]; } B;
    __shared__ double srm_sm[KSMAX];

    const int tid = threadIdx.x;
    const int b   = blockIdx.x;
    const int c0  = blockIdx.y * 16;

    if (tid < KSMAX) srm_sm[tid] = (tid < Ks) ? (double)srm[tid] : 0.0;

    const int cg = tid & 3,  tg = tid >> 2;    // GEMM tile: c=4cg+j, t=4tg+i
    const int tl = tid & 63, wv = tid >> 6;    // x staging
    const int ew = tid & 15, cw = tid >> 4;    // w staging

    double acc[4][4];
#pragma unroll
    for (int i = 0; i < 4; ++i)
#pragma unroll
        for (int j = 0; j < 4; ++j) acc[i][j] = 0.0;

    float4 xr[4];
    float  wr = 0.f;

    // stage chunk 0 (16 e)
#pragma unroll
    for (int r = 0; r < 4; ++r)
        xr[r] = *(const float4*)&xg[((size_t)b * EMBD + 4 * wv + r) * TT + 4 * tl];
    wr = W1[(size_t)(c0 + cw) * EMBD + ew];
#pragma unroll
    for (int r = 0; r < 4; ++r)
        *(float4*)&A.x[(4 * wv + r) * XSTR + 4 * tl] = xr[r];
    B.w[ew * WSTR + cw] = (double)wr;
    __syncthreads();

    const int NCH = (EMBD + 15) / 16;  // 19
    for (int ch = 0; ch < NCH; ++ch) {
        const int ecur = min(16, EMBD - ch * 16);
        const int e0n  = (ch + 1) * 16;
        const int ecn  = EMBD - e0n;
        if (ch + 1 < NCH) {            // register prefetch of next chunk
#pragma unroll
            for (int r = 0; r < 4; ++r) {
                const int e = 4 * wv + r;
                if (e < ecn)
                    xr[r] = *(const float4*)&xg[((size_t)b * EMBD + e0n + e) * TT + 4 * tl];
            }
            if (ew < ecn) wr = W1[(size_t)(c0 + cw) * EMBD + e0n + ew];
        }
        const float*  xp = &A.x[4 * tg];
        const double* wp = &B.w[4 * cg];
#pragma unroll 4
        for (int e = 0; e < ecur; ++e) {
            const float4  xv = *(const float4*)xp;
            const double2 wa = *(const double2*)wp;
            const double2 wb = *(const double2*)(wp + 2);
            const double xd0 = (double)xv.x, xd1 = (double)xv.y;
            const double xd2 = (double)xv.z, xd3 = (double)xv.w;
            acc[0][0] = fma(xd0, wa.x, acc[0][0]);
            acc[0][1] = fma(xd0, wa.y, acc[0][1]);
            acc[0][2] = fma(xd0, wb.x, acc[0][2]);
            acc[0][3] = fma(xd0, wb.y, acc[0][3]);
            acc[1][0] = fma(xd1, wa.x, acc[1][0]);
            acc[1][1] = fma(xd1, wa.y, acc[1][1]);
            acc[1][2] = fma(xd1, wb.x, acc[1][2]);
            acc[1][3] = fma(xd1, wb.y, acc[1][3]);
            acc[2][0] = fma(xd2, wa.x, acc[2][0]);
            acc[2][1] = fma(xd2, wa.y, acc[2][1]);
            acc[2][2] = fma(xd2, wb.x, acc[2][2]);
            acc[2][3] = fma(xd2, wb.y, acc[2][3]);
            acc[3][0] = fma(xd3, wa.x, acc[3][0]);
            acc[3][1] = fma(xd3, wa.y, acc[3][1]);
            acc[3][2] = fma(xd3, wb.x, acc[3][2]);
            acc[3][3] = fma(xd3, wb.y, acc[3][3]);
            xp += XSTR;
            wp += WSTR;
        }
        __syncthreads();               // all reads of A.x/B.w done
        if (ch + 1 < NCH) {
#pragma unroll
            for (int r = 0; r < 4; ++r) {
                const int e = 4 * wv + r;
                if (e < ecn)
                    *(float4*)&A.x[e * XSTR + 4 * tl] = xr[r];
            }
            if (ew < ecn) B.w[ew * WSTR + cw] = (double)wr;
            __syncthreads();
        }
    }

    // h (pre-psp membrane) -> LDS [c][t], stride HSTR
#pragma unroll
    for (int i = 0; i < 4; ++i)
#pragma unroll
        for (int j = 0; j < 4; ++j)
            A.h[(4 * cg + j) * HSTR + (4 * tg + i)] = acc[i][j];
    __syncthreads();

    // psp FIR: two passes of 8 outputs; j ascending -> bit-identical u
    const int cf = tid & 15, tb = tid >> 4;
    const double* hrow = &A.h[cf * HSTR];
    double pout[16];
#pragma unroll
    for (int k = 0; k < 16; ++k) pout[k] = 0.0;
#pragma unroll
    for (int pp = 0; pp < 2; ++pp) {
        const int t0 = tb * 16 + pp * 8;
        double win[8];
#pragma unroll
        for (int k = 0; k < 8; ++k) win[k] = hrow[t0 + k];
        for (int jb = 0; jb < KSMAX; jb += 8) {
#pragma unroll
            for (int jj = 0; jj < 8; ++jj) {
                const double sj = srm_sm[jb + jj];
#pragma unroll
                for (int i = 0; i < 8; ++i)
                    pout[pp * 8 + i] = fma(win[(8 + i - jj) & 7], sj, pout[pp * 8 + i]);
                const int idx = t0 - (jb + jj) - 1;
                win[(7 - jj) & 7] = (idx >= 0) ? hrow[idx] : 0.0;
            }
        }
    }
    __syncthreads();                   // all FIR reads done before overwrite
#pragma unroll
    for (int k = 0; k < 16; ++k)
        A.h[cf * HSTR + tb * 16 + k] = pout[k];
    __syncthreads();

    // spike scan: 16 lanes, one per channel
    if (tid < 16) {
        double fut[FUTN], rsh[FUTN];
#pragma unroll
        for (int i = 0; i < FUTN; ++i) {
            fut[i] = (i + 1 < Kr) ? (double)refk[i + 1] : 0.0;
            rsh[i] = 0.0;
        }
        const double*  hr = &A.h[tid * HSTR];
        unsigned char* sr = &B.s[tid * 260];
        for (int t = 0; t < TT; ++t) {
            const double m  = hr[t] + rsh[0];
            const double sv = (m >= THETA) ? 1.0 : 0.0;
#pragma unroll
            for (int i = 0; i < FUTN - 1; ++i) rsh[i] = fma(sv, fut[i], rsh[i + 1]);
            rsh[FUTN - 1] = sv * fut[FUTN - 1];
            sr[t] = (unsigned char)(sv != 0.0 ? 1 : 0);
        }
    }
    __syncthreads();

    // spikes -> global (uchar, coalesced via uint)
    {
        const int tl2 = tid & 63;
#pragma unroll
        for (int r = 0; r < 4; ++r) {
            const int c = (tid >> 6) + 4 * r;
            const unsigned int v = *(const unsigned int*)&B.s[c * 260 + 4 * tl2];
            *(unsigned int*)&s1[((size_t)b * HIDD + c0 + c) * TT + 4 * tl2] = v;
        }
    }
}

// ---------------- layer 2a: m2 = W2 . s1 (f64), parallel over b x t ---------
__global__ __launch_bounds__(256, 2)
void layer2a_kernel(const unsigned char* __restrict__ s1,
                    const double* __restrict__ w2d, double* __restrict__ m2)
{
    __shared__ double w2l[OUTC * HIDD];    // 40 KB
    __shared__ double red[4][OUTC][65];    // 20.8 KB

    const int tid = threadIdx.x;
    const int b = blockIdx.x, q = blockIdx.y;
    const int tl = tid & 63, hq = tid >> 6;
    const int t  = q * 64 + tl;

    for (int u = tid; u < OUTC * HIDD; u += 256) w2l[u] = w2d[u];
    __syncthreads();

    double p[OUTC];
#pragma unroll
    for (int oc = 0; oc < OUTC; ++oc) p[oc] = 0.0;

    const unsigned char* sp = s1 + ((size_t)b * HIDD + hq * 128) * TT + t;
    for (int h0 = 0; h0 < 128; ++h0) {
        const double sv = (double)sp[(size_t)h0 * TT];
        const int h = hq * 128 + h0;
#pragma unroll
        for (int oc = 0; oc < OUTC; ++oc)
            p[oc] = fma(sv, w2l[oc * HIDD + h], p[oc]);
    }
#pragma unroll
    for (int oc = 0; oc < OUTC; ++oc) red[hq][oc][tl] = p[oc];
    __syncthreads();

    for (int u = tid; u < OUTC * 64; u += 256) {
        const int oc = u >> 6, t2 = u & 63;
        const double s = ((red[0][oc][t2] + red[1][oc][t2]) +
                          red[2][oc][t2]) + red[3][oc][t2];
        m2[((size_t)b * OUTC + oc) * TT + q * 64 + t2] = s;
    }
}

// ---------------- layer 2b: FIR + spike scan on m2 --------------------------
__global__ __launch_bounds__(256)
void layer2b_kernel(const double* __restrict__ m2, const float* __restrict__ srm,
                    const float* __restrict__ refk, float* __restrict__ out,
                    int Ks, int Kr)
{
    __shared__ double mh[OUTC][257];
    __shared__ double uh[OUTC][257];
    __shared__ double srm_sm[KSMAX];
    __shared__ unsigned char s2[OUTC][260];

    const int tid = threadIdx.x;       // == t
    const int b   = blockIdx.x;

    if (tid < KSMAX) srm_sm[tid] = (tid < Ks) ? (double)srm[tid] : 0.0;
    for (int u = tid; u < OUTC * TT; u += 256)
        mh[u >> 8][u & 255] = m2[(size_t)b * OUTC * TT + u];
    __syncthreads();

    double p[OUTC];
#pragma unroll
    for (int oc = 0; oc < OUTC; ++oc) p[oc] = 0.0;
    for (int j = 0; j < KSMAX; ++j) {
        const int idx = tid - j;
        if (idx >= 0) {
            const double sj = srm_sm[j];
#pragma unroll
            for (int oc = 0; oc < OUTC; ++oc)
                p[oc] = fma(mh[oc][idx], sj, p[oc]);
        }
    }
#pragma unroll
    for (int oc = 0; oc < OUTC; ++oc) uh[oc][tid] = p[oc];
    __syncthreads();

    if (tid < OUTC) {
        double fut[FUTN], rsh[FUTN];
#pragma unroll
        for (int i = 0; i < FUTN; ++i) {
            fut[i] = (i + 1 < Kr) ? (double)refk[i + 1] : 0.0;
            rsh[i] = 0.0;
        }
        for (int t = 0; t < TT; ++t) {
            const double m  = uh[tid][t] + rsh[0];
            const double sv = (m >= THETA) ? 1.0 : 0.0;
#pragma unroll
            for (int i = 0; i < FUTN - 1; ++i) rsh[i] = fma(sv, fut[i], rsh[i + 1]);
            rsh[FUTN - 1] = sv * fut[FUTN - 1];
            s2[tid][t] = (unsigned char)(sv != 0.0 ? 1 : 0);
        }
    }
    __syncthreads();

    for (int u = tid; u < OUTC * TT; u += 256)
        out[(size_t)b * OUTC * TT + u] = (float)s2[u >> 8][u & 255];
}

extern "C" void kernel_launch(void* const* d_in, const int* in_sizes, int n_in,
                              void* d_out, int out_size, void* d_ws, size_t ws_size,
                              hipStream_t stream)
{
    const int*   feed = (const int*)  d_in[0];
    const float* emb  = (const float*)d_in[1];
    const float* W1   = (const float*)d_in[2];
    const float* W2   = (const float*)d_in[3];
    const float* srm  = (const float*)d_in[4];
    const float* refk = (const float*)d_in[5];
    const int Ks = in_sizes[4];
    const int Kr = in_sizes[5];

    unsigned char* s1c = (unsigned char*)d_ws;                       // 8,388,608 B
    float*  xg  = (float*) ((char*)d_ws + 8388608);                  // 19,660,800 B
    double* m2  = (double*)((char*)d_ws + 8388608);                  // overlaps xg (dead after layer1)
    double* w2d = (double*)((char*)d_ws + 8388608 + 19660800);       // 40,960 B
    float*  out = (float*)d_out;

    prep_kernel   <<<dim3(BB, 9),  256, 0, stream>>>(feed, emb, W2, xg, w2d);
    layer1_kernel <<<dim3(BB, 32), 256, 0, stream>>>(xg, W1, srm, refk, s1c, Ks, Kr);
    layer2a_kernel<<<dim3(BB, 4),  256, 0, stream>>>(s1c, w2d, m2);
    layer2b_kernel<<<dim3(BB),     256, 0, stream>>>(m2, srm, refk, out, Ks, Kr);
}